// Round 6
// baseline (1444.156 us; speedup 1.0000x reference)
//
#include <hip/hip_runtime.h>

#define SEQ   8192
#define DIM   1280
#define NH    16
#define HD    80
#define HDP   96
#define NSEG  8
#define SEGL  1024
#define SCALING 0.11180339887498949f  // 80^-0.5

typedef __bf16 bf16x8 __attribute__((ext_vector_type(8)));
typedef float  f32x4  __attribute__((ext_vector_type(4)));

__device__ __forceinline__ unsigned short f2bf(float x) {
    union { float f; unsigned u; } v; v.f = x;
    unsigned r = v.u + 0x7fffu + ((v.u >> 16) & 1u);
    return (unsigned short)(r >> 16);
}
__device__ __forceinline__ float bf2f(unsigned short h) {
    union { unsigned u; float f; } v; v.u = ((unsigned)h) << 16;
    return v.f;
}
__device__ __forceinline__ void glds16(const void* g, void* l) {
    __builtin_amdgcn_global_load_lds(
        (const __attribute__((address_space(1))) unsigned int*)g,
        (__attribute__((address_space(3))) unsigned int*)l, 16, 0, 0);
}

// ---------------------------------------------------------------------------
// Kernel 1: fp32->bf16 conversion of hidden/qkv_w/proj_w + zero q/k pads
// ---------------------------------------------------------------------------
__global__ void prep_kernel(const float* __restrict__ hs, const float* __restrict__ qw,
                            const float* __restrict__ pw,
                            short* __restrict__ hsb, short* __restrict__ qwb,
                            short* __restrict__ pwb,
                            short* __restrict__ qbf, short* __restrict__ kbf)
{
    const int N1 = SEQ * DIM / 4;          // 2621440 float4 chunks
    const int N2 = 3 * DIM * DIM / 4;      // 1228800
    const int N3 = DIM * DIM / 4;          // 409600
    const int NZH = NSEG * NH * SEGL * 2;  // 262144 zero-units (16B) per array
    const int total = N1 + N2 + N3 + 2 * NZH;
    for (int u = blockIdx.x * blockDim.x + threadIdx.x; u < total;
         u += gridDim.x * blockDim.x) {
        if (u < N1 + N2 + N3) {
            const float* src; short* dst; int i;
            if (u < N1)           { src = hs; dst = hsb; i = u; }
            else if (u < N1 + N2) { src = qw; dst = qwb; i = u - N1; }
            else                  { src = pw; dst = pwb; i = u - N1 - N2; }
            float4 f = ((const float4*)src)[i];
            ushort4 r;
            r.x = f2bf(f.x); r.y = f2bf(f.y); r.z = f2bf(f.z); r.w = f2bf(f.w);
            ((ushort4*)dst)[i] = r;
        } else {
            int z = u - (N1 + N2 + N3);
            short* base = (z < NZH) ? qbf : kbf;
            int rr = z & (NZH - 1);          // NZH is a power of 2
            int row = rr >> 1, half = rr & 1;
            float4 zero = make_float4(0.f, 0.f, 0.f, 0.f);
            *(float4*)(base + (long)row * HDP + HD + half * 8) = zero;
        }
    }
}

// ---------------------------------------------------------------------------
// Kernel 2/5: bf16 GEMM C = A @ B^T (A:[M][K], B:[N][K] both row-major, K=1280)
// MODE 0: QKV epilogue (bias + scatter; q/k -> [pair][r][HDP], v -> TRANSPOSED
//         [pair][d][r] so attention PV B-frags are contiguous 16B loads)
// MODE 1: proj epilogue (bias + fp32 store)
// ---------------------------------------------------------------------------
template <int MODE>
__launch_bounds__(256)
__global__ void gemm_kernel(const short* __restrict__ A, const short* __restrict__ B,
                            const float* __restrict__ bias,
                            short* __restrict__ q, short* __restrict__ k,
                            short* __restrict__ v, float* __restrict__ outf)
{
    __shared__ __align__(16) short As[128 * 64];
    __shared__ __align__(16) short Bs[128 * 64];
    const int K = DIM;
    int tid = threadIdx.x;
    int lane = tid & 63, wid = tid >> 6;
    int l15 = lane & 15, lh = lane >> 4;
    int m0 = blockIdx.y * 128, n0 = blockIdx.x * 128;
    int wr = wid >> 1, wc = wid & 1;
    f32x4 acc[4][4] = {};
    int srow = lane >> 3;        // 0..7 (row within 8-row chunk)
    int scol = (lane & 7) * 8;   // element col within 64

    for (int kb = 0; kb < K; kb += 64) {
        for (int i = 0; i < 4; i++) {
            int c = wid * 4 + i;   // 16 chunks of 8 rows x 64 cols
            glds16(A + (long)(m0 + c * 8 + srow) * K + kb + scol, As + c * 512);
            glds16(B + (long)(n0 + c * 8 + srow) * K + kb + scol, Bs + c * 512);
        }
        __syncthreads();
        for (int ks = 0; ks < 2; ks++) {
            bf16x8 af[4], bf[4];
            int ko = ks * 32 + lh * 8;
            for (int rb = 0; rb < 4; rb++)
                af[rb] = *(const bf16x8*)&As[(wr * 64 + rb * 16 + l15) * 64 + ko];
            for (int cb = 0; cb < 4; cb++)
                bf[cb] = *(const bf16x8*)&Bs[(wc * 64 + cb * 16 + l15) * 64 + ko];
            for (int rb = 0; rb < 4; rb++)
                for (int cb = 0; cb < 4; cb++)
                    acc[rb][cb] = __builtin_amdgcn_mfma_f32_16x16x32_bf16(
                        af[rb], bf[cb], acc[rb][cb], 0, 0, 0);
        }
        __syncthreads();
    }

    int mb = m0 + wr * 64, nb = n0 + wc * 64;
    if (MODE == 0) {
        for (int cb = 0; cb < 4; cb++) {
            int n = nb + cb * 16 + l15;
            float bn = bias[n];
            int which = n / DIM;
            int rem = n - which * DIM;
            int h = rem / HD;
            int d = rem - h * HD;
            for (int rb = 0; rb < 4; rb++)
                for (int j = 0; j < 4; j++) {
                    int m = mb + rb * 16 + lh * 4 + j;
                    int seg = m >> 10, r = m & 1023;
                    float val = acc[rb][cb][j] + bn;
                    long pair = (long)(seg * NH + h);
                    unsigned short bv = f2bf(val);
                    if (which == 0)      q[(pair * SEGL + r) * HDP + d] = (short)bv;
                    else if (which == 1) k[(pair * SEGL + r) * HDP + d] = (short)bv;
                    else                 v[(pair * HD + d) * SEGL + r] = (short)bv;
                }
        }
    } else {
        for (int cb = 0; cb < 4; cb++) {
            int n = nb + cb * 16 + l15;
            float bn = bias[n];
            for (int rb = 0; rb < 4; rb++)
                for (int j = 0; j < 4; j++) {
                    int m = mb + rb * 16 + lh * 4 + j;
                    outf[(long)m * DIM + n] = acc[rb][cb][j] + bn;
                }
        }
    }
}

// ---------------------------------------------------------------------------
// Kernel 3: RoPE on q,k (in place); SCALING folded into q
// ---------------------------------------------------------------------------
__global__ void rope_kernel(short* __restrict__ q, short* __restrict__ k,
                            const float* __restrict__ cs, const float* __restrict__ sn)
{
    int idx = blockIdx.x * blockDim.x + threadIdx.x;   // SEQ*NH*40 threads
    int p = idx / (NH * 40);
    int rem = idx - p * (NH * 40);
    int h = rem / 40;
    int dp = rem - h * 40;
    int seg = p >> 10, r = p & 1023;
    long base = ((long)(seg * NH + h) * SEGL + r) * HDP;
    float c0 = cs[p * HD + dp],      s0 = sn[p * HD + dp];
    float c1 = cs[p * HD + dp + 40], s1 = sn[p * HD + dp + 40];
    float a = bf2f((unsigned short)q[base + dp]);
    float b = bf2f((unsigned short)q[base + dp + 40]);
    q[base + dp]      = (short)f2bf((a * c0 - b * s0) * SCALING);
    q[base + dp + 40] = (short)f2bf((b * c1 + a * s1) * SCALING);
    a = bf2f((unsigned short)k[base + dp]);
    b = bf2f((unsigned short)k[base + dp + 40]);
    k[base + dp]      = (short)f2bf(a * c0 - b * s0);
    k[base + dp + 40] = (short)f2bf(b * c1 + a * s1);
}

// ---------------------------------------------------------------------------
// Kernel 4: barrier-free flash attention. Each wave owns 16 q-rows.
// Swapped QK^T: S^T = mfma(K, Q) so lane = one q-row (col=l15), k in regs.
// Online softmax fully in-lane (+2 shfl_xor). P via wave-local LDS (no
// barrier, same-wave RAW). V pre-transposed [pair][d][r]: PV B-frags are
// direct contiguous 16B global loads. Zero __syncthreads in the kernel.
// ---------------------------------------------------------------------------
__launch_bounds__(256)
__global__ void attn_kernel(const short* __restrict__ qg, const short* __restrict__ kg,
                            const short* __restrict__ vtg, short* __restrict__ out)
{
    __shared__ __align__(16) short plds[4][16 * 72];   // per-wave P tile, pad 72
    int tid = threadIdx.x;
    int lane = tid & 63, wid = tid >> 6;
    int l15 = lane & 15, lh = lane >> 4;
    int pair = blockIdx.x;            // seg*NH + h  (128 pairs; %8 -> XCD-local)
    int qt = blockIdx.y;              // 0..15
    int seg = pair >> 4, h = pair & 15;
    const short* qh = qg + (long)pair * SEGL * HDP;
    const short* kh = kg + (long)pair * SEGL * HDP;
    const short* vh = vtg + (long)pair * HD * SEGL;
    int q0 = qt * 64 + wid * 16;

    // Q fragments (B-operand: col=l15 -> q-row, kk = ks*32 + lh*8)
    bf16x8 qf[3];
#pragma unroll
    for (int ks = 0; ks < 3; ks++)
        qf[ks] = *(const bf16x8*)&qh[(q0 + l15) * HDP + ks * 32 + lh * 8];

    f32x4 o[5] = {};
    float m = -1e30f, l = 0.f;
    short* pl = plds[wid];

    for (int t = 0; t < 16; t++) {
        const short* kt = kh + (long)t * 64 * HDP;
        // S^T: 4 tiles of [k=16][q=16]; lane holds q=l15, k = t*64+tt*16+lh*4+j
        f32x4 st[4] = {};
#pragma unroll
        for (int tt = 0; tt < 4; tt++)
#pragma unroll
            for (int ks = 0; ks < 3; ks++) {
                bf16x8 kf = *(const bf16x8*)&kt[(tt * 16 + l15) * HDP + ks * 32 + lh * 8];
                st[tt] = __builtin_amdgcn_mfma_f32_16x16x32_bf16(kf, qf[ks], st[tt], 0, 0, 0);
            }
        // online-softmax row max: in-lane over 16 + xor 16,32 (lanes sharing l15)
        float rmax = st[0][0];
#pragma unroll
        for (int tt = 0; tt < 4; tt++)
#pragma unroll
            for (int j = 0; j < 4; j++) rmax = fmaxf(rmax, st[tt][j]);
        rmax = fmaxf(rmax, __shfl_xor(rmax, 16));
        rmax = fmaxf(rmax, __shfl_xor(rmax, 32));
        float mn = fmaxf(m, rmax);
        float f = __expf(m - mn);
        m = mn;
        // P = exp(S-m) -> bf16 -> wave-local LDS (8B stores); row sum
        float ps = 0.f;
#pragma unroll
        for (int tt = 0; tt < 4; tt++) {
            float p0 = __expf(st[tt][0] - mn);
            float p1 = __expf(st[tt][1] - mn);
            float p2 = __expf(st[tt][2] - mn);
            float p3 = __expf(st[tt][3] - mn);
            ps += (p0 + p1) + (p2 + p3);
            ushort4 pk;
            pk.x = f2bf(p0); pk.y = f2bf(p1); pk.z = f2bf(p2); pk.w = f2bf(p3);
            *(ushort4*)&pl[l15 * 72 + tt * 16 + lh * 4] = pk;
        }
        ps += __shfl_xor(ps, 16);
        ps += __shfl_xor(ps, 32);
        l = l * f + ps;
        // rescale O: row q = lh*4+j needs f from lane (lh*4+j)
        float fr[4];
#pragma unroll
        for (int j = 0; j < 4; j++) fr[j] = __shfl(f, lh * 4 + j);
#pragma unroll
        for (int cb = 0; cb < 5; cb++)
#pragma unroll
            for (int j = 0; j < 4; j++) o[cb][j] *= fr[j];
        // PV: A = P (row=q=l15 from LDS), B = V^T (col=l15 -> d, direct global)
        const short* vk = vh + t * 64;
#pragma unroll
        for (int ks = 0; ks < 2; ks++) {
            bf16x8 pa = *(const bf16x8*)&pl[l15 * 72 + ks * 32 + lh * 8];
#pragma unroll
            for (int cb = 0; cb < 5; cb++) {
                bf16x8 vb = *(const bf16x8*)&vk[(cb * 16 + l15) * SEGL + ks * 32 + lh * 8];
                o[cb] = __builtin_amdgcn_mfma_f32_16x16x32_bf16(pa, vb, o[cb], 0, 0, 0);
            }
        }
    }

    float linv[4];
#pragma unroll
    for (int j = 0; j < 4; j++) linv[j] = 1.f / __shfl(l, lh * 4 + j);
    long orow = (long)seg * SEGL + qt * 64 + wid * 16;
#pragma unroll
    for (int cb = 0; cb < 5; cb++)
#pragma unroll
        for (int j = 0; j < 4; j++)
            out[(orow + lh * 4 + j) * DIM + h * HD + cb * 16 + l15] =
                (short)f2bf(o[cb][j] * linv[j]);
}

// ---------------------------------------------------------------------------
extern "C" void kernel_launch(void* const* d_in, const int* in_sizes, int n_in,
                              void* d_out, int out_size, void* d_ws, size_t ws_size,
                              hipStream_t stream)
{
    const float* hs = (const float*)d_in[0];
    const float* cs = (const float*)d_in[1];
    const float* sn = (const float*)d_in[2];
    const float* qw = (const float*)d_in[3];
    const float* qb = (const float*)d_in[4];
    const float* pw = (const float*)d_in[5];
    const float* pb = (const float*)d_in[6];
    float* out = (float*)d_out;

    short* hsb = (short*)d_ws;                         // [8192][1280] bf16
    short* qwb = hsb + (long)SEQ * DIM;                // [3840][1280]
    short* pwb = qwb + (long)3 * DIM * DIM;            // [1280][1280]
    short* qbf = pwb + (long)DIM * DIM;                // [128][1024][96]
    short* kbf = qbf + (long)NSEG * NH * SEGL * HDP;   // [128][1024][96]
    short* vbf = kbf + (long)NSEG * NH * SEGL * HDP;   // [128][80][1024]  (V^T)
    short* aob = vbf + (long)NSEG * NH * HD * SEGL;    // [8192][1280] bf16

    prep_kernel<<<dim3(2048), dim3(256), 0, stream>>>(hs, qw, pw, hsb, qwb, pwb, qbf, kbf);
    gemm_kernel<0><<<dim3(30, 64), dim3(256), 0, stream>>>(hsb, qwb, qb, qbf, kbf, vbf, nullptr);
    rope_kernel<<<dim3(SEQ * NH * 40 / 256), dim3(256), 0, stream>>>(qbf, kbf, cs, sn);
    attn_kernel<<<dim3(128, 16), dim3(256), 0, stream>>>(qbf, kbf, vbf, aob);
    gemm_kernel<1><<<dim3(10, 64), dim3(256), 0, stream>>>(aob, pwb, pb, nullptr, nullptr, nullptr, out);
}

// Round 7
// 582.946 us; speedup vs baseline: 2.4773x; 2.4773x over previous
//
#include <hip/hip_runtime.h>

#define SEQ   8192
#define DIM   1280
#define NH    16
#define HD    80
#define HDP   96
#define NSEG  8
#define SEGL  1024
#define SCALING 0.11180339887498949f  // 80^-0.5

typedef __bf16 bf16x8 __attribute__((ext_vector_type(8)));
typedef float  f32x4  __attribute__((ext_vector_type(4)));

__device__ __forceinline__ unsigned short f2bf(float x) {
    union { float f; unsigned u; } v; v.f = x;
    unsigned r = v.u + 0x7fffu + ((v.u >> 16) & 1u);
    return (unsigned short)(r >> 16);
}
__device__ __forceinline__ float bf2f(unsigned short h) {
    union { unsigned u; float f; } v; v.u = ((unsigned)h) << 16;
    return v.f;
}
__device__ __forceinline__ void glds16(const void* g, void* l) {
    __builtin_amdgcn_global_load_lds(
        (const __attribute__((address_space(1))) unsigned int*)g,
        (__attribute__((address_space(3))) unsigned int*)l, 16, 0, 0);
}

// ---------------------------------------------------------------------------
// Kernel 1: fp32->bf16 conversion of hidden/qkv_w/proj_w + zero q/k pads
// ---------------------------------------------------------------------------
__global__ void prep_kernel(const float* __restrict__ hs, const float* __restrict__ qw,
                            const float* __restrict__ pw,
                            short* __restrict__ hsb, short* __restrict__ qwb,
                            short* __restrict__ pwb,
                            short* __restrict__ qbf, short* __restrict__ kbf)
{
    const int N1 = SEQ * DIM / 4;          // 2621440 float4 chunks
    const int N2 = 3 * DIM * DIM / 4;      // 1228800
    const int N3 = DIM * DIM / 4;          // 409600
    const int NZH = NSEG * NH * SEGL * 2;  // 262144 zero-units (16B) per array
    const int total = N1 + N2 + N3 + 2 * NZH;
    for (int u = blockIdx.x * blockDim.x + threadIdx.x; u < total;
         u += gridDim.x * blockDim.x) {
        if (u < N1 + N2 + N3) {
            const float* src; short* dst; int i;
            if (u < N1)           { src = hs; dst = hsb; i = u; }
            else if (u < N1 + N2) { src = qw; dst = qwb; i = u - N1; }
            else                  { src = pw; dst = pwb; i = u - N1 - N2; }
            float4 f = ((const float4*)src)[i];
            ushort4 r;
            r.x = f2bf(f.x); r.y = f2bf(f.y); r.z = f2bf(f.z); r.w = f2bf(f.w);
            ((ushort4*)dst)[i] = r;
        } else {
            int z = u - (N1 + N2 + N3);
            short* base = (z < NZH) ? qbf : kbf;
            int rr = z & (NZH - 1);          // NZH is a power of 2
            int row = rr >> 1, half = rr & 1;
            float4 zero = make_float4(0.f, 0.f, 0.f, 0.f);
            *(float4*)(base + (long)row * HDP + HD + half * 8) = zero;
        }
    }
}

// ---------------------------------------------------------------------------
// Kernel 2/5: bf16 GEMM C = A @ B^T (A:[M][K], B:[N][K] both row-major, K=1280)
// MODE 0: QKV epilogue. q/k -> [pair][r][HDP] direct scatter (32B groups).
//         V blocks (n0 >= 2560 -> whole 128x128 tile is V) go through an LDS
//         transpose so the [pair][d][r] store is 16B-coalesced along r
//         (direct scatter was 2B stores @ 2048B stride -> 3.9 GB write traffic).
// MODE 1: proj epilogue (bias + fp32 store)
// ---------------------------------------------------------------------------
template <int MODE>
__launch_bounds__(256)
__global__ void gemm_kernel(const short* __restrict__ A, const short* __restrict__ B,
                            const float* __restrict__ bias,
                            short* __restrict__ q, short* __restrict__ k,
                            short* __restrict__ v, float* __restrict__ outf)
{
    __shared__ __align__(16) short smem[128 * 136];   // 34 KB; As/Bs + transpose buf
    short* As = smem;              // 128*64 shorts
    short* Bs = smem + 128 * 64;   // 128*64 shorts
    const int K = DIM;
    int tid = threadIdx.x;
    int lane = tid & 63, wid = tid >> 6;
    int l15 = lane & 15, lh = lane >> 4;
    int m0 = blockIdx.y * 128, n0 = blockIdx.x * 128;
    int wr = wid >> 1, wc = wid & 1;
    f32x4 acc[4][4] = {};
    int srow = lane >> 3;        // 0..7 (row within 8-row chunk)
    int scol = (lane & 7) * 8;   // element col within 64

    for (int kb = 0; kb < K; kb += 64) {
        for (int i = 0; i < 4; i++) {
            int c = wid * 4 + i;   // 16 chunks of 8 rows x 64 cols
            glds16(A + (long)(m0 + c * 8 + srow) * K + kb + scol, As + c * 512);
            glds16(B + (long)(n0 + c * 8 + srow) * K + kb + scol, Bs + c * 512);
        }
        __syncthreads();
        for (int ks = 0; ks < 2; ks++) {
            bf16x8 af[4], bf[4];
            int ko = ks * 32 + lh * 8;
            for (int rb = 0; rb < 4; rb++)
                af[rb] = *(const bf16x8*)&As[(wr * 64 + rb * 16 + l15) * 64 + ko];
            for (int cb = 0; cb < 4; cb++)
                bf[cb] = *(const bf16x8*)&Bs[(wc * 64 + cb * 16 + l15) * 64 + ko];
            for (int rb = 0; rb < 4; rb++)
                for (int cb = 0; cb < 4; cb++)
                    acc[rb][cb] = __builtin_amdgcn_mfma_f32_16x16x32_bf16(
                        af[rb], bf[cb], acc[rb][cb], 0, 0, 0);
        }
        __syncthreads();
    }

    int mb = m0 + wr * 64, nb = n0 + wc * 64;
    if (MODE == 0) {
        if (n0 >= 2 * DIM) {
            // ---- pure-V block: LDS transpose -> coalesced [d][r] writes ----
            for (int cb = 0; cb < 4; cb++) {
                int nLoc = wc * 64 + cb * 16 + l15;
                float bn = bias[n0 + nLoc];
                for (int rb = 0; rb < 4; rb++) {
                    ushort4 pk;
                    pk.x = f2bf(acc[rb][cb][0] + bn);
                    pk.y = f2bf(acc[rb][cb][1] + bn);
                    pk.z = f2bf(acc[rb][cb][2] + bn);
                    pk.w = f2bf(acc[rb][cb][3] + bn);
                    int mLoc = wr * 64 + rb * 16 + lh * 4;
                    *(ushort4*)&smem[nLoc * 136 + mLoc] = pk;
                }
            }
            __syncthreads();
            int seg = m0 >> 10, r0 = m0 & 1023;
            long vbase = ((long)seg * DIM + (n0 - 2 * DIM)) * SEGL + r0;
            for (int it = 0; it < 8; it++) {
                int row = it * 16 + (tid >> 4);    // 0..127  (= hd offset)
                int col = (tid & 15) * 8;          // 0..120  (= r offset)
                *(float4*)&v[vbase + (long)row * SEGL + col] =
                    *(const float4*)&smem[row * 136 + col];
            }
        } else {
            // ---- q/k block: row-major scatter (32B per lane-group) ----
            for (int cb = 0; cb < 4; cb++) {
                int n = nb + cb * 16 + l15;
                float bn = bias[n];
                int which = n / DIM;               // 0 or 1 here
                int rem = n - which * DIM;
                int h = rem / HD;
                int d = rem - h * HD;
                for (int rb = 0; rb < 4; rb++)
                    for (int j = 0; j < 4; j++) {
                        int m = mb + rb * 16 + lh * 4 + j;
                        int seg = m >> 10, r = m & 1023;
                        float val = acc[rb][cb][j] + bn;
                        long pair = (long)(seg * NH + h);
                        unsigned short bv = f2bf(val);
                        if (which == 0) q[(pair * SEGL + r) * HDP + d] = (short)bv;
                        else            k[(pair * SEGL + r) * HDP + d] = (short)bv;
                    }
            }
        }
    } else {
        for (int cb = 0; cb < 4; cb++) {
            int n = nb + cb * 16 + l15;
            float bn = bias[n];
            for (int rb = 0; rb < 4; rb++)
                for (int j = 0; j < 4; j++) {
                    int m = mb + rb * 16 + lh * 4 + j;
                    outf[(long)m * DIM + n] = acc[rb][cb][j] + bn;
                }
        }
    }
}

// ---------------------------------------------------------------------------
// Kernel 3: RoPE on q,k (in place); SCALING folded into q
// ---------------------------------------------------------------------------
__global__ void rope_kernel(short* __restrict__ q, short* __restrict__ k,
                            const float* __restrict__ cs, const float* __restrict__ sn)
{
    int idx = blockIdx.x * blockDim.x + threadIdx.x;   // SEQ*NH*40 threads
    int p = idx / (NH * 40);
    int rem = idx - p * (NH * 40);
    int h = rem / 40;
    int dp = rem - h * 40;
    int seg = p >> 10, r = p & 1023;
    long base = ((long)(seg * NH + h) * SEGL + r) * HDP;
    float c0 = cs[p * HD + dp],      s0 = sn[p * HD + dp];
    float c1 = cs[p * HD + dp + 40], s1 = sn[p * HD + dp + 40];
    float a = bf2f((unsigned short)q[base + dp]);
    float b = bf2f((unsigned short)q[base + dp + 40]);
    q[base + dp]      = (short)f2bf((a * c0 - b * s0) * SCALING);
    q[base + dp + 40] = (short)f2bf((b * c1 + a * s1) * SCALING);
    a = bf2f((unsigned short)k[base + dp]);
    b = bf2f((unsigned short)k[base + dp + 40]);
    k[base + dp]      = (short)f2bf(a * c0 - b * s0);
    k[base + dp + 40] = (short)f2bf(b * c1 + a * s1);
}

// ---------------------------------------------------------------------------
// Kernel 4: barrier-free flash attention. Each wave owns 16 q-rows.
// Swapped QK^T: S^T = mfma(K, Q) so lane = one q-row (col=l15), k in regs.
// Online softmax fully in-lane (+2 shfl_xor). P via wave-local LDS (no
// barrier, same-wave RAW). V pre-transposed [pair][d][r]: PV B-frags are
// direct contiguous 16B global loads. Zero __syncthreads in the kernel.
// ---------------------------------------------------------------------------
__launch_bounds__(256)
__global__ void attn_kernel(const short* __restrict__ qg, const short* __restrict__ kg,
                            const short* __restrict__ vtg, short* __restrict__ out)
{
    __shared__ __align__(16) short plds[4][16 * 72];   // per-wave P tile, pad 72
    int tid = threadIdx.x;
    int lane = tid & 63, wid = tid >> 6;
    int l15 = lane & 15, lh = lane >> 4;
    int pair = blockIdx.x;            // seg*NH + h  (128 pairs; %8 -> XCD-local)
    int qt = blockIdx.y;              // 0..15
    int seg = pair >> 4, h = pair & 15;
    const short* qh = qg + (long)pair * SEGL * HDP;
    const short* kh = kg + (long)pair * SEGL * HDP;
    const short* vh = vtg + (long)pair * HD * SEGL;
    int q0 = qt * 64 + wid * 16;

    // Q fragments (B-operand: col=l15 -> q-row, kk = ks*32 + lh*8)
    bf16x8 qf[3];
#pragma unroll
    for (int ks = 0; ks < 3; ks++)
        qf[ks] = *(const bf16x8*)&qh[(q0 + l15) * HDP + ks * 32 + lh * 8];

    f32x4 o[5] = {};
    float m = -1e30f, l = 0.f;
    short* pl = plds[wid];

    for (int t = 0; t < 16; t++) {
        const short* kt = kh + (long)t * 64 * HDP;
        // S^T: 4 tiles of [k=16][q=16]; lane holds q=l15, k = t*64+tt*16+lh*4+j
        f32x4 st[4] = {};
#pragma unroll
        for (int tt = 0; tt < 4; tt++)
#pragma unroll
            for (int ks = 0; ks < 3; ks++) {
                bf16x8 kf = *(const bf16x8*)&kt[(tt * 16 + l15) * HDP + ks * 32 + lh * 8];
                st[tt] = __builtin_amdgcn_mfma_f32_16x16x32_bf16(kf, qf[ks], st[tt], 0, 0, 0);
            }
        // online-softmax row max: in-lane over 16 + xor 16,32 (lanes sharing l15)
        float rmax = st[0][0];
#pragma unroll
        for (int tt = 0; tt < 4; tt++)
#pragma unroll
            for (int j = 0; j < 4; j++) rmax = fmaxf(rmax, st[tt][j]);
        rmax = fmaxf(rmax, __shfl_xor(rmax, 16));
        rmax = fmaxf(rmax, __shfl_xor(rmax, 32));
        float mn = fmaxf(m, rmax);
        float f = __expf(m - mn);
        m = mn;
        // P = exp(S-m) -> bf16 -> wave-local LDS (8B stores); row sum
        float ps = 0.f;
#pragma unroll
        for (int tt = 0; tt < 4; tt++) {
            float p0 = __expf(st[tt][0] - mn);
            float p1 = __expf(st[tt][1] - mn);
            float p2 = __expf(st[tt][2] - mn);
            float p3 = __expf(st[tt][3] - mn);
            ps += (p0 + p1) + (p2 + p3);
            ushort4 pk;
            pk.x = f2bf(p0); pk.y = f2bf(p1); pk.z = f2bf(p2); pk.w = f2bf(p3);
            *(ushort4*)&pl[l15 * 72 + tt * 16 + lh * 4] = pk;
        }
        ps += __shfl_xor(ps, 16);
        ps += __shfl_xor(ps, 32);
        l = l * f + ps;
        // rescale O: row q = lh*4+j needs f from lane (lh*4+j)
        float fr[4];
#pragma unroll
        for (int j = 0; j < 4; j++) fr[j] = __shfl(f, lh * 4 + j);
#pragma unroll
        for (int cb = 0; cb < 5; cb++)
#pragma unroll
            for (int j = 0; j < 4; j++) o[cb][j] *= fr[j];
        // PV: A = P (row=q=l15 from LDS), B = V^T (col=l15 -> d, direct global)
        const short* vk = vh + t * 64;
#pragma unroll
        for (int ks = 0; ks < 2; ks++) {
            bf16x8 pa = *(const bf16x8*)&pl[l15 * 72 + ks * 32 + lh * 8];
#pragma unroll
            for (int cb = 0; cb < 5; cb++) {
                bf16x8 vb = *(const bf16x8*)&vk[(cb * 16 + l15) * SEGL + ks * 32 + lh * 8];
                o[cb] = __builtin_amdgcn_mfma_f32_16x16x32_bf16(pa, vb, o[cb], 0, 0, 0);
            }
        }
    }

    float linv[4];
#pragma unroll
    for (int j = 0; j < 4; j++) linv[j] = 1.f / __shfl(l, lh * 4 + j);
    long orow = (long)seg * SEGL + qt * 64 + wid * 16;
#pragma unroll
    for (int cb = 0; cb < 5; cb++)
#pragma unroll
        for (int j = 0; j < 4; j++)
            out[(orow + lh * 4 + j) * DIM + h * HD + cb * 16 + l15] =
                (short)f2bf(o[cb][j] * linv[j]);
}

// ---------------------------------------------------------------------------
extern "C" void kernel_launch(void* const* d_in, const int* in_sizes, int n_in,
                              void* d_out, int out_size, void* d_ws, size_t ws_size,
                              hipStream_t stream)
{
    const float* hs = (const float*)d_in[0];
    const float* cs = (const float*)d_in[1];
    const float* sn = (const float*)d_in[2];
    const float* qw = (const float*)d_in[3];
    const float* qb = (const float*)d_in[4];
    const float* pw = (const float*)d_in[5];
    const float* pb = (const float*)d_in[6];
    float* out = (float*)d_out;

    short* hsb = (short*)d_ws;                         // [8192][1280] bf16
    short* qwb = hsb + (long)SEQ * DIM;                // [3840][1280]
    short* pwb = qwb + (long)3 * DIM * DIM;            // [1280][1280]
    short* qbf = pwb + (long)DIM * DIM;                // [128][1024][96]
    short* kbf = qbf + (long)NSEG * NH * SEGL * HDP;   // [128][1024][96]
    short* vbf = kbf + (long)NSEG * NH * SEGL * HDP;   // [128][80][1024]  (V^T)
    short* aob = vbf + (long)NSEG * NH * HD * SEGL;    // [8192][1280] bf16

    prep_kernel<<<dim3(2048), dim3(256), 0, stream>>>(hs, qw, pw, hsb, qwb, pwb, qbf, kbf);
    gemm_kernel<0><<<dim3(30, 64), dim3(256), 0, stream>>>(hsb, qwb, qb, qbf, kbf, vbf, nullptr);
    rope_kernel<<<dim3(SEQ * NH * 40 / 256), dim3(256), 0, stream>>>(qbf, kbf, cs, sn);
    attn_kernel<<<dim3(128, 16), dim3(256), 0, stream>>>(qbf, kbf, vbf, aob);
    gemm_kernel<1><<<dim3(10, 64), dim3(256), 0, stream>>>(aob, pwb, pb, nullptr, nullptr, nullptr, out);
}